// Round 18
// baseline (264.640 us; speedup 1.0000x reference)
//
#include <hip/hip_runtime.h>
#include <stdint.h>

// AttentionBlock: GN -> QKV -> softmax(QK^T/sqrt(C)) V -> proj + residual
// B=4, C=256, H=W=64, N=4096, groups=8 (32 ch/group)
// All matmuls bf16 MFMA (fp32 accumulate). fp32 threshold 0.1 absmax.
//
// Round 18 = round 10/17 attn structure + chunk-major K/V LDS (r11-verified
// zero-conflict): K per half [32 chunk16B][32 key], V per half
// [4 chunk16B][256 ch]. All fragment reads contiguous per 16-lane group ->
// conflict-free b128; staging dests stay linear for global_load_lds.
// Removes the measured 1.03e7 bank-conflict cycles (~13%/iter).

#define B_ 4
#define C_ 256
#define N_ 4096
#define KVB 32

using bf16x8 = __attribute__((ext_vector_type(8))) __bf16;
using f32x4  = __attribute__((ext_vector_type(4))) float;

__device__ __forceinline__ uint16_t f2bf(float f) {
    uint32_t u = __float_as_uint(f);
    u = (u + 0x7fffu + ((u >> 16) & 1u)) >> 16;   // RNE
    return (uint16_t)u;
}

__device__ __forceinline__ f32x4 mfma16(bf16x8 a, bf16x8 b, f32x4 c) {
    return __builtin_amdgcn_mfma_f32_16x16x32_bf16(a, b, c, 0, 0, 0);
}

__device__ __forceinline__ void gload16(const void* g, void* l) {
    __builtin_amdgcn_global_load_lds(
        (const __attribute__((address_space(1))) uint32_t*)g,
        (__attribute__((address_space(3))) uint32_t*)l, 16, 0, 0);
}

// ---------------- cast weights to bf16 ----------------
__global__ __launch_bounds__(256) void cast_weights(
        const float* __restrict__ qkvw, const float* __restrict__ projw,
        uint16_t* __restrict__ qkvwb, uint16_t* __restrict__ projwb) {
    int i = blockIdx.x * 256 + threadIdx.x;
    if (i < 768 * 256) qkvwb[i] = f2bf(qkvw[i]);
    int j = i - 768 * 256;
    if (j >= 0 && j < 256 * 256) projwb[j] = f2bf(projw[j]);
}

// ---------------- GroupNorm stats, two-stage ----------------
__global__ __launch_bounds__(256) void gn_stats1(const float* __restrict__ x,
                                                 float2* __restrict__ part) {
    int i = blockIdx.x;
    const float4* p = reinterpret_cast<const float4*>(x + (size_t)i * 4096);
    float s = 0.f, ss = 0.f;
    #pragma unroll
    for (int j = 0; j < 4; j++) {
        float4 v = p[threadIdx.x + j * 256];
        s  += v.x + v.y + v.z + v.w;
        ss += v.x*v.x + v.y*v.y + v.z*v.z + v.w*v.w;
    }
    #pragma unroll
    for (int d = 32; d > 0; d >>= 1) { s += __shfl_down(s, d); ss += __shfl_down(ss, d); }
    __shared__ float rs[4], rss[4];
    int wid = threadIdx.x >> 6;
    if ((threadIdx.x & 63) == 0) { rs[wid] = s; rss[wid] = ss; }
    __syncthreads();
    if (threadIdx.x == 0) {
        float2 o;
        o.x = rs[0] + rs[1] + rs[2] + rs[3];
        o.y = rss[0] + rss[1] + rss[2] + rss[3];
        part[i] = o;
    }
}
__global__ __launch_bounds__(1024) void gn_stats2(const float2* __restrict__ part,
                                                  float* __restrict__ stats) {
    int t = threadIdx.x;
    int g = t >> 5, j = t & 31;
    float2 v = part[g * 32 + j];
    float s = v.x, ss = v.y;
    #pragma unroll
    for (int d = 16; d > 0; d >>= 1) { s += __shfl_xor(s, d); ss += __shfl_xor(ss, d); }
    if (j == 0) {
        float mean = s / 131072.f;
        float var  = ss / 131072.f - mean * mean;
        stats[g * 2]     = mean;
        stats[g * 2 + 1] = rsqrtf(var + 1e-5f);
    }
}

// ---------------- GN apply + transpose: hT[b][n][c] bf16 ----------------
__global__ __launch_bounds__(256) void gn_apply(
        const float* __restrict__ x, const float* __restrict__ gnw,
        const float* __restrict__ gnb, const float* __restrict__ stats,
        uint16_t* __restrict__ hT) {
    int nb = blockIdx.x * 64, cb = blockIdx.y * 64, b = blockIdx.z;
    __shared__ uint16_t lds[64][64];          // [n][c]
    int t = threadIdx.x;
    int c_l = t >> 4;
    int n4  = (t & 15) * 4;
    #pragma unroll
    for (int i = 0; i < 4; i++) {
        int c = cb + c_l + 16 * i;
        int sg = b * 8 + (c >> 5);
        float mean = stats[sg * 2], rstd = stats[sg * 2 + 1];
        float sc = gnw[c] * rstd;
        float sh = gnb[c] - mean * sc;
        float4 v = *reinterpret_cast<const float4*>(x + ((size_t)b * C_ + c) * N_ + nb + n4);
        lds[n4 + 0][c_l + 16 * i] = f2bf(fmaf(v.x, sc, sh));
        lds[n4 + 1][c_l + 16 * i] = f2bf(fmaf(v.y, sc, sh));
        lds[n4 + 2][c_l + 16 * i] = f2bf(fmaf(v.z, sc, sh));
        lds[n4 + 3][c_l + 16 * i] = f2bf(fmaf(v.w, sc, sh));
    }
    __syncthreads();
    int n_l = t >> 2, c16 = (t & 3) * 16;
    uint4* dst = reinterpret_cast<uint4*>(hT + ((size_t)b * N_ + nb + n_l) * C_ + cb + c16);
    const uint4* sp = reinterpret_cast<const uint4*>(&lds[n_l][c16]);
    dst[0] = sp[0]; dst[1] = sp[1];
}

// ---------------- QKV GEMM (coalesced stores via LDS tile) ----------------
// q,k transposed [n][o]; q pre-scaled by 1/16. v kept [o'][n].
__global__ __launch_bounds__(256) void qkv_gemm(
        const uint16_t* __restrict__ Wb, const float* __restrict__ qkvb,
        const uint16_t* __restrict__ hT, uint16_t* __restrict__ qT,
        uint16_t* __restrict__ kT, uint16_t* __restrict__ vO) {
    int nt = blockIdx.x, ot = blockIdx.y, b = blockIdx.z;
    int lane = threadIdx.x & 63, w = threadIdx.x >> 6;
    int l15 = lane & 15, g = lane >> 4;
    const uint16_t* hTb = hT + (size_t)b * N_ * C_;
    f32x4 z = {0.f, 0.f, 0.f, 0.f};
    f32x4 acc[4] = {z, z, z, z};
    __shared__ uint16_t tile[64 * 68];        // 8.5 KB, pitch 68

    if (ot < 8) {   // q,k : D[row=n][col=o]; tile[n_local][o_local]
        int nrow = nt * 64 + w * 16 + l15;
        const bf16x8* Arow = reinterpret_cast<const bf16x8*>(hTb + (size_t)nrow * C_);
        #pragma unroll
        for (int kk = 0; kk < 8; kk++) {
            bf16x8 a = Arow[kk * 4 + g];
            #pragma unroll
            for (int j = 0; j < 4; j++) {
                int orow = ot * 64 + j * 16 + l15;
                bf16x8 bfr = reinterpret_cast<const bf16x8*>(Wb + (size_t)orow * C_)[kk * 4 + g];
                acc[j] = mfma16(a, bfr, acc[j]);
            }
        }
        bool isq = (ot < 4);
        float scl = isq ? 0.0625f : 1.0f;
        #pragma unroll
        for (int j = 0; j < 4; j++) {
            int o = ot * 64 + j * 16 + l15;
            float bias = qkvb[o];
            #pragma unroll
            for (int r = 0; r < 4; r++)
                tile[(w * 16 + g * 4 + r) * 68 + j * 16 + l15] =
                    f2bf((acc[j][r] + bias) * scl);
        }
        __syncthreads();
        uint16_t* dstb = isq ? (qT + (size_t)b * N_ * C_ + ot * 64)
                             : (kT + (size_t)b * N_ * C_ + (ot - 4) * 64);
        int t = threadIdx.x;
        #pragma unroll
        for (int i = 0; i < 2; i++) {
            int idx = i * 256 + t;
            int row = idx >> 3, cc = (idx & 7) * 8;
            uint4 val = *reinterpret_cast<const uint4*>(&tile[row * 68 + cc]);
            *reinterpret_cast<uint4*>(dstb + (size_t)(nt * 64 + row) * C_ + cc) = val;
        }
    } else {        // v : D[row=o'][col=n]; tile[o_local][n_local]
        int orow = ot * 64 + w * 16 + l15;   // 512..767
        const bf16x8* Arow = reinterpret_cast<const bf16x8*>(Wb + (size_t)orow * C_);
        #pragma unroll
        for (int kk = 0; kk < 8; kk++) {
            bf16x8 a = Arow[kk * 4 + g];
            #pragma unroll
            for (int j = 0; j < 4; j++) {
                int nrow = nt * 64 + j * 16 + l15;
                bf16x8 bfr = reinterpret_cast<const bf16x8*>(hTb + (size_t)nrow * C_)[kk * 4 + g];
                acc[j] = mfma16(a, bfr, acc[j]);
            }
        }
        #pragma unroll
        for (int j = 0; j < 4; j++) {
            #pragma unroll
            for (int r = 0; r < 4; r++) {
                int o = ot * 64 + w * 16 + g * 4 + r;
                tile[(w * 16 + g * 4 + r) * 68 + j * 16 + l15] =
                    f2bf(acc[j][r] + qkvb[o]);
            }
        }
        __syncthreads();
        uint16_t* dstb = vO + (size_t)b * C_ * N_ + (size_t)(ot - 8) * 64 * N_;
        int t = threadIdx.x;
        #pragma unroll
        for (int i = 0; i < 2; i++) {
            int idx = i * 256 + t;
            int row = idx >> 3, cc = (idx & 7) * 8;
            uint4 val = *reinterpret_cast<const uint4*>(&tile[row * 68 + cc]);
            *reinterpret_cast<uint4*>(dstb + (size_t)row * N_ + nt * 64 + cc) = val;
        }
    }
}

// ---------------- Flash attention: 8 waves, 2-way key split, chunk-major ----
// Block: 512 thr = 8 waves. Wave w: rowgroup rg = w&3 (rows nb+rg*16),
// key half h = w>>2 (tiles h*64+i). Per (buf,half) chunk-major LDS:
//   Kt: [32 chunk16B][32 key]   (chunk = 8 ch)  16 KB
//   Vt: [4 chunk16B][256 ch]    (chunk = 8 key) 16 KB
// All QK/PV fragment reads are contiguous 256B per 16-lane group ->
// conflict-free. ONE barrier/iter (double-buffered). Static-max softmax.
// Epilogue: half 1 writes (O,l) to LDS, half 0 merges + stores.
__global__ __launch_bounds__(512, 2) void attn_kernel(
        const uint16_t* __restrict__ qT, const uint16_t* __restrict__ kT,
        const uint16_t* __restrict__ vO, uint16_t* __restrict__ h2T) {
    int blk = blockIdx.x;
    int xx = blk & 7;
    int b  = xx >> 1;
    int qt = (blk >> 3) * 2 + (xx & 1);       // 0..63
    int lane = threadIdx.x & 63, w = threadIdx.x >> 6;   // w in 0..7
    int rg = w & 3, h = w >> 2;
    int l15 = lane & 15, g = lane >> 4;
    const uint16_t* qTb = qT + (size_t)b * N_ * C_;
    const uint16_t* kTb = kT + (size_t)b * N_ * C_;
    const uint16_t* vb  = vO + (size_t)b * C_ * N_;
    int nb = qt * 64 + rg * 16;

    __shared__ uint16_t Kt[2][2][32 * 256];   // [buf][half][chunk*256+key*8]
    __shared__ uint16_t Vt[2][2][4 * 2048];   // [buf][half][chunk*2048+ch*8]
    __shared__ uint16_t plds[8][16][40];      // 10 KB, wave-private padded

    // Q fragments (once)
    bf16x8 afr[8];
    {
        const bf16x8* qrow = reinterpret_cast<const bf16x8*>(qTb + (size_t)(nb + l15) * C_);
        #pragma unroll
        for (int kk = 0; kk < 8; kk++) afr[kk] = qrow[kk * 4 + g];
    }

    f32x4 z = {0.f, 0.f, 0.f, 0.f};
    f32x4 acc[16];
    #pragma unroll
    for (int i = 0; i < 16; i++) acc[i] = z;
    float l_r[4] = {0.f, 0.f, 0.f, 0.f};

    // wave (rg,h) stages: K chunks rg*8..+8 (4 instr x 2 chunks),
    //                     V ch rg*64..+64 all 4 chunks (4 instr x 1 chunk)
    auto stage = [&](int buf, int mb) {
        #pragma unroll
        for (int i = 0; i < 4; i++) {
            int c2 = rg * 8 + i * 2;          // lane: chunk=c2+(l>>5), key=l&31
            gload16(kTb + (size_t)(mb + (lane & 31)) * C_ + (c2 + (lane >> 5)) * 8,
                    &Kt[buf][h][c2 * 256]);
        }
        #pragma unroll
        for (int i = 0; i < 4; i++) {         // lane: ch = rg*64 + lane
            gload16(vb + (size_t)(rg * 64 + lane) * N_ + mb + i * 8,
                    &Vt[buf][h][i * 2048 + rg * 64 * 8]);
        }
    };

    stage(0, h * 64 * KVB);
    __syncthreads();

    for (int mt = 0; mt < 64; mt++) {
        int buf = mt & 1;
        if (mt + 1 < 64) stage(buf ^ 1, (h * 64 + mt + 1) * KVB);

        // ---- QK^T: K fragment = chunk kk*4+g, keys l15 / 16+l15 ----
        f32x4 sc0 = z, sc1 = z;
        #pragma unroll
        for (int kk = 0; kk < 8; kk++) {
            int ci = (kk * 4 + g) * 256;
            bf16x8 k0 = *reinterpret_cast<const bf16x8*>(&Kt[buf][h][ci + l15 * 8]);
            bf16x8 k1 = *reinterpret_cast<const bf16x8*>(&Kt[buf][h][ci + (16 + l15) * 8]);
            sc0 = mfma16(afr[kk], k0, sc0);
            sc1 = mfma16(afr[kk], k1, sc1);
        }

        // ---- static-max softmax ----
        #pragma unroll
        for (int r = 0; r < 4; r++) {
            float p0 = __expf(sc0[r]);
            float p1 = __expf(sc1[r]);
            l_r[r] += p0 + p1;
            plds[w][g * 4 + r][l15]      = f2bf(p0);
            plds[w][g * 4 + r][16 + l15] = f2bf(p1);
        }
        // plds wave-private: no barrier needed

        bf16x8 pb = *reinterpret_cast<const bf16x8*>(&plds[w][l15][g * 8]);

        // ---- PV: V fragment = chunk g (keys g*8..+8), ch ct*16+l15 ----
        #pragma unroll
        for (int ct = 0; ct < 16; ct++) {
            bf16x8 va = *reinterpret_cast<const bf16x8*>(
                &Vt[buf][h][g * 2048 + (ct * 16 + l15) * 8]);
            acc[ct] = mfma16(va, pb, acc[ct]);
        }

        __syncthreads();   // drains vmcnt; both halves advance together
    }

    // ---- reduce l partials within wave; map to per-lane q-row = l15 ----
    #pragma unroll
    for (int d = 1; d < 16; d <<= 1) {
        #pragma unroll
        for (int r = 0; r < 4; r++) l_r[r] += __shfl_xor(l_r[r], d);
    }
    int bsrc = (l15 >> 2) * 16;
    int sel = l15 & 3;
    float s0 = __shfl(l_r[0], bsrc), s1 = __shfl(l_r[1], bsrc),
          s2 = __shfl(l_r[2], bsrc), s3 = __shfl(l_r[3], bsrc);
    float lv = (sel == 0) ? s0 : (sel == 1) ? s1 : (sel == 2) ? s2 : s3;

    // ---- cross-half merge via LDS (reuse Kt as fp32 O-buffer, Vt for l) ----
    float* Olds = reinterpret_cast<float*>(&Kt[0][0][0]);   // [64 rows][256 ch] f32
    float* lbuf = reinterpret_cast<float*>(&Vt[0][0][0]);   // [64] f32
    if (h == 1) {
        if (lane < 16) lbuf[rg * 16 + l15] = lv;
        #pragma unroll
        for (int ct = 0; ct < 16; ct++)
            *reinterpret_cast<f32x4*>(&Olds[(size_t)(rg * 16 + l15) * 256 + ct * 16 + g * 4]) = acc[ct];
    }
    __syncthreads();
    if (h == 0) {
        float inv = 1.0f / (lv + lbuf[rg * 16 + l15]);
        uint16_t* row = h2T + ((size_t)b * N_ + nb + l15) * C_;
        #pragma unroll
        for (int ct = 0; ct < 16; ct++) {
            f32x4 o2 = *reinterpret_cast<const f32x4*>(
                &Olds[(size_t)(rg * 16 + l15) * 256 + ct * 16 + g * 4]);
            uint32_t lo = f2bf((acc[ct][0] + o2[0]) * inv) |
                          ((uint32_t)f2bf((acc[ct][1] + o2[1]) * inv) << 16);
            uint32_t hi = f2bf((acc[ct][2] + o2[2]) * inv) |
                          ((uint32_t)f2bf((acc[ct][3] + o2[3]) * inv) << 16);
            *reinterpret_cast<uint32_t*>(row + ct * 16 + g * 4)     = lo;
            *reinterpret_cast<uint32_t*>(row + ct * 16 + g * 4 + 2) = hi;
        }
    }
}

// ---------------- proj GEMM + bias + residual ----------------
__global__ __launch_bounds__(256) void proj_gemm(
        const uint16_t* __restrict__ Pwb, const float* __restrict__ pb,
        const uint16_t* __restrict__ h2T, const float* __restrict__ x,
        float* __restrict__ out) {
    int nt = blockIdx.x, ct = blockIdx.y, b = blockIdx.z;
    int lane = threadIdx.x & 63, w = threadIdx.x >> 6;
    int l15 = lane & 15, g = lane >> 4;
    const uint16_t* h2Tb = h2T + (size_t)b * N_ * C_;
    f32x4 z = {0.f, 0.f, 0.f, 0.f};
    f32x4 acc[4] = {z, z, z, z};
    int crow = ct * 64 + w * 16 + l15;
    const bf16x8* Arow = reinterpret_cast<const bf16x8*>(Pwb + (size_t)crow * C_);
    #pragma unroll
    for (int kk = 0; kk < 8; kk++) {
        bf16x8 a = Arow[kk * 4 + g];
        #pragma unroll
        for (int j = 0; j < 4; j++) {
            bf16x8 bfr = reinterpret_cast<const bf16x8*>(
                h2Tb + (size_t)(nt * 64 + j * 16 + l15) * C_)[kk * 4 + g];
            acc[j] = mfma16(a, bfr, acc[j]);
        }
    }
    #pragma unroll
    for (int j = 0; j < 4; j++) {
        #pragma unroll
        for (int r = 0; r < 4; r++) {
            int c = ct * 64 + w * 16 + g * 4 + r;
            int n = nt * 64 + j * 16 + l15;
            size_t idx = ((size_t)b * C_ + c) * N_ + n;
            out[idx] = x[idx] + acc[j][r] + pb[c];
        }
    }
}

extern "C" void kernel_launch(void* const* d_in, const int* in_sizes, int n_in,
                              void* d_out, int out_size, void* d_ws, size_t ws_size,
                              hipStream_t stream) {
    const float* x      = (const float*)d_in[0];
    const float* gn_w   = (const float*)d_in[1];
    const float* gn_b   = (const float*)d_in[2];
    const float* qkv_w  = (const float*)d_in[3];
    const float* qkv_b  = (const float*)d_in[4];
    const float* proj_w = (const float*)d_in[5];
    const float* proj_b = (const float*)d_in[6];
    float* out = (float*)d_out;

    char* ws = (char*)d_ws;
    float*    stats  = (float*)(ws);                          // 256 B
    float2*   part   = (float2*)(ws + 8192);                  // 8 KB
    uint16_t* qkvwb  = (uint16_t*)(ws + 65536);               // 384 KB
    uint16_t* projwb = (uint16_t*)(ws + 65536 + 768 * 256 * 2);
    uint16_t* hT     = (uint16_t*)(ws + (size_t)(1)  * (1 << 20));  // 8 MB [B][N][C]
    uint16_t* qT     = (uint16_t*)(ws + (size_t)(9)  * (1 << 20));  // 8 MB [B][N][C]
    uint16_t* kT     = (uint16_t*)(ws + (size_t)(17) * (1 << 20));  // 8 MB [B][N][C]
    uint16_t* vO     = (uint16_t*)(ws + (size_t)(25) * (1 << 20));  // 8 MB [B][C][N]
    uint16_t* h2T    = (uint16_t*)(ws + (size_t)(33) * (1 << 20));  // 8 MB [B][N][C]

    cast_weights<<<dim3(1024), dim3(256), 0, stream>>>(qkv_w, proj_w, qkvwb, projwb);
    gn_stats1<<<dim3(1024), dim3(256), 0, stream>>>(x, part);
    gn_stats2<<<dim3(1), dim3(1024), 0, stream>>>(part, stats);
    gn_apply<<<dim3(64, 4, 4), dim3(256), 0, stream>>>(x, gn_w, gn_b, stats, hT);
    qkv_gemm<<<dim3(64, 12, 4), dim3(256), 0, stream>>>(qkvwb, qkv_b, hT, qT, kT, vO);
    attn_kernel<<<dim3(256), dim3(512), 0, stream>>>(qT, kT, vO, h2T);
    proj_gemm<<<dim3(64, 4, 4), dim3(256), 0, stream>>>(projwb, proj_b, h2T, x, out);
}

// Round 21
// 210.151 us; speedup vs baseline: 1.2593x; 1.2593x over previous
//
#include <hip/hip_runtime.h>
#include <stdint.h>

// AttentionBlock: GN -> QKV -> softmax(QK^T/sqrt(C)) V -> proj + residual
// B=4, C=256, H=W=64, N=4096, groups=8 (32 ch/group)
// All matmuls bf16 MFMA (fp32 accumulate). fp32 threshold 0.1 absmax.
//
// Round 21 = round 19/20 resubmit #2 (dead container blocked both pushes).
// r17 base (222us) + PV channel-split dedup: all 4 rowgroup-waves of a half
// read the SAME 16 V fragments. Restructured: wave (rg,h) computes
// O[ch rg*64..+64][all 64 rows] -> 4 V-frags + 4 cross-wave P-frags = 8 PV
// LDS reads/wave vs 17. Total LDS issue -27% (the measured bottleneck).
// Cost: +1 barrier/iter (plds cross-wave). Staging/QK/softmax r17-verbatim.

#define B_ 4
#define C_ 256
#define N_ 4096
#define KVB 32

using bf16x8 = __attribute__((ext_vector_type(8))) __bf16;
using f32x4  = __attribute__((ext_vector_type(4))) float;

__device__ __forceinline__ uint16_t f2bf(float f) {
    uint32_t u = __float_as_uint(f);
    u = (u + 0x7fffu + ((u >> 16) & 1u)) >> 16;   // RNE
    return (uint16_t)u;
}

__device__ __forceinline__ f32x4 mfma16(bf16x8 a, bf16x8 b, f32x4 c) {
    return __builtin_amdgcn_mfma_f32_16x16x32_bf16(a, b, c, 0, 0, 0);
}

__device__ __forceinline__ void gload16(const void* g, void* l) {
    __builtin_amdgcn_global_load_lds(
        (const __attribute__((address_space(1))) uint32_t*)g,
        (__attribute__((address_space(3))) uint32_t*)l, 16, 0, 0);
}

// ---------------- cast weights to bf16 ----------------
__global__ __launch_bounds__(256) void cast_weights(
        const float* __restrict__ qkvw, const float* __restrict__ projw,
        uint16_t* __restrict__ qkvwb, uint16_t* __restrict__ projwb) {
    int i = blockIdx.x * 256 + threadIdx.x;
    if (i < 768 * 256) qkvwb[i] = f2bf(qkvw[i]);
    int j = i - 768 * 256;
    if (j >= 0 && j < 256 * 256) projwb[j] = f2bf(projw[j]);
}

// ---------------- GroupNorm stats, two-stage ----------------
__global__ __launch_bounds__(256) void gn_stats1(const float* __restrict__ x,
                                                 float2* __restrict__ part) {
    int i = blockIdx.x;
    const float4* p = reinterpret_cast<const float4*>(x + (size_t)i * 4096);
    float s = 0.f, ss = 0.f;
    #pragma unroll
    for (int j = 0; j < 4; j++) {
        float4 v = p[threadIdx.x + j * 256];
        s  += v.x + v.y + v.z + v.w;
        ss += v.x*v.x + v.y*v.y + v.z*v.z + v.w*v.w;
    }
    #pragma unroll
    for (int d = 32; d > 0; d >>= 1) { s += __shfl_down(s, d); ss += __shfl_down(ss, d); }
    __shared__ float rs[4], rss[4];
    int wid = threadIdx.x >> 6;
    if ((threadIdx.x & 63) == 0) { rs[wid] = s; rss[wid] = ss; }
    __syncthreads();
    if (threadIdx.x == 0) {
        float2 o;
        o.x = rs[0] + rs[1] + rs[2] + rs[3];
        o.y = rss[0] + rss[1] + rss[2] + rss[3];
        part[i] = o;
    }
}
__global__ __launch_bounds__(1024) void gn_stats2(const float2* __restrict__ part,
                                                  float* __restrict__ stats) {
    int t = threadIdx.x;
    int g = t >> 5, j = t & 31;
    float2 v = part[g * 32 + j];
    float s = v.x, ss = v.y;
    #pragma unroll
    for (int d = 16; d > 0; d >>= 1) { s += __shfl_xor(s, d); ss += __shfl_xor(ss, d); }
    if (j == 0) {
        float mean = s / 131072.f;
        float var  = ss / 131072.f - mean * mean;
        stats[g * 2]     = mean;
        stats[g * 2 + 1] = rsqrtf(var + 1e-5f);
    }
}

// ---------------- GN apply + transpose: hT[b][n][c] bf16 ----------------
__global__ __launch_bounds__(256) void gn_apply(
        const float* __restrict__ x, const float* __restrict__ gnw,
        const float* __restrict__ gnb, const float* __restrict__ stats,
        uint16_t* __restrict__ hT) {
    int nb = blockIdx.x * 64, cb = blockIdx.y * 64, b = blockIdx.z;
    __shared__ uint16_t lds[64][64];          // [n][c]
    int t = threadIdx.x;
    int c_l = t >> 4;
    int n4  = (t & 15) * 4;
    #pragma unroll
    for (int i = 0; i < 4; i++) {
        int c = cb + c_l + 16 * i;
        int sg = b * 8 + (c >> 5);
        float mean = stats[sg * 2], rstd = stats[sg * 2 + 1];
        float sc = gnw[c] * rstd;
        float sh = gnb[c] - mean * sc;
        float4 v = *reinterpret_cast<const float4*>(x + ((size_t)b * C_ + c) * N_ + nb + n4);
        lds[n4 + 0][c_l + 16 * i] = f2bf(fmaf(v.x, sc, sh));
        lds[n4 + 1][c_l + 16 * i] = f2bf(fmaf(v.y, sc, sh));
        lds[n4 + 2][c_l + 16 * i] = f2bf(fmaf(v.z, sc, sh));
        lds[n4 + 3][c_l + 16 * i] = f2bf(fmaf(v.w, sc, sh));
    }
    __syncthreads();
    int n_l = t >> 2, c16 = (t & 3) * 16;
    uint4* dst = reinterpret_cast<uint4*>(hT + ((size_t)b * N_ + nb + n_l) * C_ + cb + c16);
    const uint4* sp = reinterpret_cast<const uint4*>(&lds[n_l][c16]);
    dst[0] = sp[0]; dst[1] = sp[1];
}

// ---------------- QKV GEMM (coalesced stores via LDS tile) ----------------
__global__ __launch_bounds__(256) void qkv_gemm(
        const uint16_t* __restrict__ Wb, const float* __restrict__ qkvb,
        const uint16_t* __restrict__ hT, uint16_t* __restrict__ qT,
        uint16_t* __restrict__ kT, uint16_t* __restrict__ vO) {
    int nt = blockIdx.x, ot = blockIdx.y, b = blockIdx.z;
    int lane = threadIdx.x & 63, w = threadIdx.x >> 6;
    int l15 = lane & 15, g = lane >> 4;
    const uint16_t* hTb = hT + (size_t)b * N_ * C_;
    f32x4 z = {0.f, 0.f, 0.f, 0.f};
    f32x4 acc[4] = {z, z, z, z};
    __shared__ uint16_t tile[64 * 68];        // 8.5 KB, pitch 68

    if (ot < 8) {   // q,k : D[row=n][col=o]; tile[n_local][o_local]
        int nrow = nt * 64 + w * 16 + l15;
        const bf16x8* Arow = reinterpret_cast<const bf16x8*>(hTb + (size_t)nrow * C_);
        #pragma unroll
        for (int kk = 0; kk < 8; kk++) {
            bf16x8 a = Arow[kk * 4 + g];
            #pragma unroll
            for (int j = 0; j < 4; j++) {
                int orow = ot * 64 + j * 16 + l15;
                bf16x8 bfr = reinterpret_cast<const bf16x8*>(Wb + (size_t)orow * C_)[kk * 4 + g];
                acc[j] = mfma16(a, bfr, acc[j]);
            }
        }
        bool isq = (ot < 4);
        float scl = isq ? 0.0625f : 1.0f;
        #pragma unroll
        for (int j = 0; j < 4; j++) {
            int o = ot * 64 + j * 16 + l15;
            float bias = qkvb[o];
            #pragma unroll
            for (int r = 0; r < 4; r++)
                tile[(w * 16 + g * 4 + r) * 68 + j * 16 + l15] =
                    f2bf((acc[j][r] + bias) * scl);
        }
        __syncthreads();
        uint16_t* dstb = isq ? (qT + (size_t)b * N_ * C_ + ot * 64)
                             : (kT + (size_t)b * N_ * C_ + (ot - 4) * 64);
        int t = threadIdx.x;
        #pragma unroll
        for (int i = 0; i < 2; i++) {
            int idx = i * 256 + t;
            int row = idx >> 3, cc = (idx & 7) * 8;
            uint4 val = *reinterpret_cast<const uint4*>(&tile[row * 68 + cc]);
            *reinterpret_cast<uint4*>(dstb + (size_t)(nt * 64 + row) * C_ + cc) = val;
        }
    } else {        // v : D[row=o'][col=n]; tile[o_local][n_local]
        int orow = ot * 64 + w * 16 + l15;   // 512..767
        const bf16x8* Arow = reinterpret_cast<const bf16x8*>(Wb + (size_t)orow * C_);
        #pragma unroll
        for (int kk = 0; kk < 8; kk++) {
            bf16x8 a = Arow[kk * 4 + g];
            #pragma unroll
            for (int j = 0; j < 4; j++) {
                int nrow = nt * 64 + j * 16 + l15;
                bf16x8 bfr = reinterpret_cast<const bf16x8*>(hTb + (size_t)nrow * C_)[kk * 4 + g];
                acc[j] = mfma16(a, bfr, acc[j]);
            }
        }
        #pragma unroll
        for (int j = 0; j < 4; j++) {
            #pragma unroll
            for (int r = 0; r < 4; r++) {
                int o = ot * 64 + w * 16 + g * 4 + r;
                tile[(w * 16 + g * 4 + r) * 68 + j * 16 + l15] =
                    f2bf(acc[j][r] + qkvb[o]);
            }
        }
        __syncthreads();
        uint16_t* dstb = vO + (size_t)b * C_ * N_ + (size_t)(ot - 8) * 64 * N_;
        int t = threadIdx.x;
        #pragma unroll
        for (int i = 0; i < 2; i++) {
            int idx = i * 256 + t;
            int row = idx >> 3, cc = (idx & 7) * 8;
            uint4 val = *reinterpret_cast<const uint4*>(&tile[row * 68 + cc]);
            *reinterpret_cast<uint4*>(dstb + (size_t)row * N_ + nt * 64 + cc) = val;
        }
    }
}

// ---------------- Flash attention: 8 waves, 2-way key split, PV dedup ------
// 512 thr: wave w -> rowgroup rg = w&3 (QK/softmax rows nb+rg*16), key half
// h = w>>2. K/V LDS layouts + staging = r17 verbatim (coalesced, dbuf).
// Iter: [stage(t+1) issue] QK(t) -> softmax(t) writes plds -> bar1 ->
// PV(t) channel-split: wave computes O[ch rg*64..+64][all 64 rows] via 4
// V-frags x 4 cross-wave P-frags -> bar2.
// Epilogue: both halves write row-sums to lbuf; h=1 writes O to Olds
// (pitch 260); h=0 merges + stores its 64-ch slice of h2T.
__global__ __launch_bounds__(512, 2) void attn_kernel(
        const uint16_t* __restrict__ qT, const uint16_t* __restrict__ kT,
        const uint16_t* __restrict__ vO, uint16_t* __restrict__ h2T) {
    int blk = blockIdx.x;
    int xx = blk & 7;
    int b  = xx >> 1;
    int qt = (blk >> 3) * 2 + (xx & 1);       // 0..63
    int lane = threadIdx.x & 63, w = threadIdx.x >> 6;   // w in 0..7
    int rg = w & 3, h = w >> 2;
    int l15 = lane & 15, g = lane >> 4;
    const uint16_t* qTb = qT + (size_t)b * N_ * C_;
    const uint16_t* kTb = kT + (size_t)b * N_ * C_;
    const uint16_t* vb  = vO + (size_t)b * C_ * N_;
    int nb = qt * 64 + rg * 16;

    __shared__ __align__(16) char smem[141312];
    uint16_t* KtB = reinterpret_cast<uint16_t*>(smem);            // [buf*2+h][8192]
    uint16_t* VtB = reinterpret_cast<uint16_t*>(smem + 65536);    // [buf*2+h][8192]
    uint16_t* plw = reinterpret_cast<uint16_t*>(smem + 131072);   // [8][16][40]

    // Q fragments (once)
    bf16x8 afr[8];
    {
        const bf16x8* qrow = reinterpret_cast<const bf16x8*>(qTb + (size_t)(nb + l15) * C_);
        #pragma unroll
        for (int kk = 0; kk < 8; kk++) afr[kk] = qrow[kk * 4 + g];
    }

    f32x4 z = {0.f, 0.f, 0.f, 0.f};
    f32x4 acc[16];                            // [ct2*4+r4]: ch rg*64+ct2*16, row r4*16
    #pragma unroll
    for (int i = 0; i < 16; i++) acc[i] = z;
    float l_r[4] = {0.f, 0.f, 0.f, 0.f};

    // r17-verbatim staging (coalesced): K rows rg*8..+8, V ch rg*64..+64
    auto stage = [&](int buf, int mb) {
        uint16_t* Ktp = KtB + (buf * 2 + h) * 8192;
        uint16_t* Vtp = VtB + (buf * 2 + h) * 8192;
        #pragma unroll
        for (int i = 0; i < 4; i++) {
            int rb = rg * 8 + i * 2;
            int r  = rb + (lane >> 5);
            int c  = (lane & 31) ^ (r & 7);
            gload16(kTb + (size_t)(mb + r) * C_ + c * 8, Ktp + rb * 256);
        }
        #pragma unroll
        for (int i = 0; i < 4; i++) {
            int cb2 = rg * 64 + i * 16;
            int ch = cb2 + (lane >> 2);
            int c  = (lane & 3) ^ ((ch >> 1) & 3);
            gload16(vb + (size_t)ch * N_ + mb + c * 8, Vtp + cb2 * 32);
        }
    };

    stage(0, h * 64 * KVB);
    __syncthreads();

    for (int mt = 0; mt < 64; mt++) {
        int buf = mt & 1;
        if (mt + 1 < 64) stage(buf ^ 1, (h * 64 + mt + 1) * KVB);
        const uint16_t* Ktp = KtB + (buf * 2 + h) * 8192;
        const uint16_t* Vtp = VtB + (buf * 2 + h) * 8192;

        // ---- QK^T (r17 verbatim) ----
        f32x4 sc0 = z, sc1 = z;
        #pragma unroll
        for (int kk = 0; kk < 8; kk++) {
            int c0 = (kk * 4 + g) ^ (l15 & 7);
            bf16x8 k0 = *reinterpret_cast<const bf16x8*>(&Ktp[l15 * 256 + c0 * 8]);
            bf16x8 k1 = *reinterpret_cast<const bf16x8*>(&Ktp[(16 + l15) * 256 + c0 * 8]);
            sc0 = mfma16(afr[kk], k0, sc0);
            sc1 = mfma16(afr[kk], k1, sc1);
        }

        // ---- static-max softmax (r17 verbatim) ----
        #pragma unroll
        for (int r = 0; r < 4; r++) {
            float p0 = __expf(sc0[r]);
            float p1 = __expf(sc1[r]);
            l_r[r] += p0 + p1;
            plw[w * 640 + (g * 4 + r) * 40 + l15]      = f2bf(p0);
            plw[w * 640 + (g * 4 + r) * 40 + 16 + l15] = f2bf(p1);
        }
        __syncthreads();   // bar1: plds visible to all waves; stage(t+1) drained

        // ---- PV channel-split: 4 V-frags x 4 P-frags ----
        bf16x8 pbr[4];
        #pragma unroll
        for (int r4 = 0; r4 < 4; r4++)
            pbr[r4] = *reinterpret_cast<const bf16x8*>(
                &plw[(h * 4 + r4) * 640 + l15 * 40 + g * 8]);
        #pragma unroll
        for (int ct2 = 0; ct2 < 4; ct2++) {
            int ch = rg * 64 + ct2 * 16 + l15;
            bf16x8 va = *reinterpret_cast<const bf16x8*>(
                &Vtp[ch * 32 + ((g ^ ((ch >> 1) & 3)) * 8)]);
            #pragma unroll
            for (int r4 = 0; r4 < 4; r4++)
                acc[ct2 * 4 + r4] = mfma16(va, pbr[r4], acc[ct2 * 4 + r4]);
        }

        __syncthreads();   // bar2: PV done before next softmax overwrites plds
    }

    // ---- reduce l partials within wave; map to per-lane q-row = l15 ----
    #pragma unroll
    for (int d = 1; d < 16; d <<= 1) {
        #pragma unroll
        for (int r = 0; r < 4; r++) l_r[r] += __shfl_xor(l_r[r], d);
    }
    int bsrc = (l15 >> 2) * 16;
    int sel = l15 & 3;
    float s0 = __shfl(l_r[0], bsrc), s1 = __shfl(l_r[1], bsrc),
          s2 = __shfl(l_r[2], bsrc), s3 = __shfl(l_r[3], bsrc);
    float lv = (sel == 0) ? s0 : (sel == 1) ? s1 : (sel == 2) ? s2 : s3;

    // ---- merge: Olds [64 qrow][pitch 260] f32 over Kt; lbuf at +98304 ----
    float* Olds = reinterpret_cast<float*>(smem);             // 66.6 KB
    float* lbuf = reinterpret_cast<float*>(smem + 98304);     // [2h][64]
    if (lane < 16) lbuf[h * 64 + rg * 16 + l15] = lv;         // row-sum for rg rows
    if (h == 1) {
        #pragma unroll
        for (int ct2 = 0; ct2 < 4; ct2++) {
            #pragma unroll
            for (int r4 = 0; r4 < 4; r4++)
                *reinterpret_cast<f32x4*>(
                    &Olds[(size_t)(r4 * 16 + l15) * 260 + rg * 64 + ct2 * 16 + g * 4]) =
                    acc[ct2 * 4 + r4];
        }
    }
    __syncthreads();
    if (h == 0) {
        #pragma unroll
        for (int r4 = 0; r4 < 4; r4++) {
            int qrow = r4 * 16 + l15;
            float inv = 1.0f / (lbuf[qrow] + lbuf[64 + qrow]);
            uint16_t* rowp = h2T + ((size_t)b * N_ + qt * 64 + qrow) * C_ + rg * 64;
            #pragma unroll
            for (int ct2 = 0; ct2 < 4; ct2++) {
                f32x4 o2 = *reinterpret_cast<const f32x4*>(
                    &Olds[(size_t)qrow * 260 + rg * 64 + ct2 * 16 + g * 4]);
                f32x4 a = acc[ct2 * 4 + r4];
                uint32_t lo = f2bf((a[0] + o2[0]) * inv) |
                              ((uint32_t)f2bf((a[1] + o2[1]) * inv) << 16);
                uint32_t hi = f2bf((a[2] + o2[2]) * inv) |
                              ((uint32_t)f2bf((a[3] + o2[3]) * inv) << 16);
                *reinterpret_cast<uint32_t*>(rowp + ct2 * 16 + g * 4)     = lo;
                *reinterpret_cast<uint32_t*>(rowp + ct2 * 16 + g * 4 + 2) = hi;
            }
        }
    }
}

// ---------------- proj GEMM + bias + residual ----------------
__global__ __launch_bounds__(256) void proj_gemm(
        const uint16_t* __restrict__ Pwb, const float* __restrict__ pb,
        const uint16_t* __restrict__ h2T, const float* __restrict__ x,
        float* __restrict__ out) {
    int nt = blockIdx.x, ct = blockIdx.y, b = blockIdx.z;
    int lane = threadIdx.x & 63, w = threadIdx.x >> 6;
    int l15 = lane & 15, g = lane >> 4;
    const uint16_t* h2Tb = h2T + (size_t)b * N_ * C_;
    f32x4 z = {0.f, 0.f, 0.f, 0.f};
    f32x4 acc[4] = {z, z, z, z};
    int crow = ct * 64 + w * 16 + l15;
    const bf16x8* Arow = reinterpret_cast<const bf16x8*>(Pwb + (size_t)crow * C_);
    #pragma unroll
    for (int kk = 0; kk < 8; kk++) {
        bf16x8 a = Arow[kk * 4 + g];
        #pragma unroll
        for (int j = 0; j < 4; j++) {
            bf16x8 bfr = reinterpret_cast<const bf16x8*>(
                h2Tb + (size_t)(nt * 64 + j * 16 + l15) * C_)[kk * 4 + g];
            acc[j] = mfma16(a, bfr, acc[j]);
        }
    }
    #pragma unroll
    for (int j = 0; j < 4; j++) {
        #pragma unroll
        for (int r = 0; r < 4; r++) {
            int c = ct * 64 + w * 16 + g * 4 + r;
            int n = nt * 64 + j * 16 + l15;
            size_t idx = ((size_t)b * C_ + c) * N_ + n;
            out[idx] = x[idx] + acc[j][r] + pb[c];
        }
    }
}

extern "C" void kernel_launch(void* const* d_in, const int* in_sizes, int n_in,
                              void* d_out, int out_size, void* d_ws, size_t ws_size,
                              hipStream_t stream) {
    const float* x      = (const float*)d_in[0];
    const float* gn_w   = (const float*)d_in[1];
    const float* gn_b   = (const float*)d_in[2];
    const float* qkv_w  = (const float*)d_in[3];
    const float* qkv_b  = (const float*)d_in[4];
    const float* proj_w = (const float*)d_in[5];
    const float* proj_b = (const float*)d_in[6];
    float* out = (float*)d_out;

    char* ws = (char*)d_ws;
    float*    stats  = (float*)(ws);                          // 256 B
    float2*   part   = (float2*)(ws + 8192);                  // 8 KB
    uint16_t* qkvwb  = (uint16_t*)(ws + 65536);               // 384 KB
    uint16_t* projwb = (uint16_t*)(ws + 65536 + 768 * 256 * 2);
    uint16_t* hT     = (uint16_t*)(ws + (size_t)(1)  * (1 << 20));  // 8 MB [B][N][C]
    uint16_t* qT     = (uint16_t*)(ws + (size_t)(9)  * (1 << 20));  // 8 MB [B][N][C]
    uint16_t* kT     = (uint16_t*)(ws + (size_t)(17) * (1 << 20));  // 8 MB [B][N][C]
    uint16_t* vO     = (uint16_t*)(ws + (size_t)(25) * (1 << 20));  // 8 MB [B][C][N]
    uint16_t* h2T    = (uint16_t*)(ws + (size_t)(33) * (1 << 20));  // 8 MB [B][N][C]

    cast_weights<<<dim3(1024), dim3(256), 0, stream>>>(qkv_w, proj_w, qkvwb, projwb);
    gn_stats1<<<dim3(1024), dim3(256), 0, stream>>>(x, part);
    gn_stats2<<<dim3(1), dim3(1024), 0, stream>>>(part, stats);
    gn_apply<<<dim3(64, 4, 4), dim3(256), 0, stream>>>(x, gn_w, gn_b, stats, hT);
    qkv_gemm<<<dim3(64, 12, 4), dim3(256), 0, stream>>>(qkvwb, qkv_b, hT, qT, kT, vO);
    attn_kernel<<<dim3(256), dim3(512), 0, stream>>>(qT, kT, vO, h2T);
    proj_gemm<<<dim3(64, 4, 4), dim3(256), 0, stream>>>(projwb, proj_b, h2T, x, out);
}